// Round 7
// baseline (258.583 us; speedup 1.0000x reference)
//
#include <hip/hip_runtime.h>
#include <hip/hip_cooperative_groups.h>
#include <hip/hip_bf16.h>
#include <stdint.h>

namespace cg = cooperative_groups;
typedef unsigned long long u64;

#define AN 15
#define HH 200
#define WW 320
#define HWSZ (HH*WW)          // 64000
#define PER (AN*HWSZ)         // 960000 anchors per image
#define NB 8
#define K_PRE 2000
#define K_POST 1000
#define SORTN 4096
#define HBINS 4096
#define CBLK 16               // compact sub-blocks per image
#define SLICE (SORTN/CBLK)    // 256 slots per compact sub-block
#define NMS_TH 0.7f
#define BBOX_CLIP_F 4.135166556742356f   // log(1000/16)
#define NBLK 256
#define NTHR 512

// padded LDS index for the sort: +1 u64 per 8 -> lane stride 72B, <=4-way conflicts
#define PHI(x) ((x) + ((x) >> 3))

__device__ __forceinline__ unsigned keyOfU(unsigned u) {
    return (u & 0x80000000u) ? ~u : (u | 0x80000000u);
}
__device__ __forceinline__ float valOf(unsigned k) {
    unsigned u = (k & 0x80000000u) ? (k ^ 0x80000000u) : ~k;
    return __uint_as_float(u);
}

__global__ __launch_bounds__(NTHR, 2)
void k_fused(const uint4* __restrict__ cls4, const float* __restrict__ regr,
             const float* __restrict__ anchors, const int* __restrict__ pih,
             const int* __restrict__ piw,
             unsigned* __restrict__ gh, unsigned* __restrict__ selT12,
             u64* __restrict__ cand, float* __restrict__ boxes_s,
             float* __restrict__ scores_s, u64* __restrict__ maskT,
             float* __restrict__ out) {
    cg::grid_group grid = cg::this_grid();
    const int bid = blockIdx.x, tid = threadIdx.x;
    __shared__ u64 smem[4652];               // 37.2 KB, reused per phase
    unsigned* sm32 = (unsigned*)smem;

    // ---------------- P0: zero gh (131072 B = 256 blocks x 32 uint4) --------
    if (tid < 32) ((uint4*)gh)[bid * 32 + tid] = make_uint4(0, 0, 0, 0);
    grid.sync();

    // ---------------- P1: histogram (32 sub-blocks per image) ---------------
    {
        int n = bid >> 5, s = bid & 31;
        unsigned* lh = sm32;                 // 2 x 4096 u32 = 32 KB
        for (int b = tid; b < 2 * HBINS; b += NTHR) lh[b] = 0;
        __syncthreads();
        unsigned* myh = lh + (tid & 1) * HBINS;
        const uint4* p = cls4 + (size_t)n * (PER / 4);
        int lo = s * 7500, hi = lo + 7500;   // PER/4/32
        int i = lo + tid;
        for (; i + NTHR < hi; i += 2 * NTHR) {
            uint4 a = p[i];
            uint4 b = p[i + NTHR];
            atomicAdd(&myh[keyOfU(a.x) >> 20], 1u);
            atomicAdd(&myh[keyOfU(a.y) >> 20], 1u);
            atomicAdd(&myh[keyOfU(a.z) >> 20], 1u);
            atomicAdd(&myh[keyOfU(a.w) >> 20], 1u);
            atomicAdd(&myh[keyOfU(b.x) >> 20], 1u);
            atomicAdd(&myh[keyOfU(b.y) >> 20], 1u);
            atomicAdd(&myh[keyOfU(b.z) >> 20], 1u);
            atomicAdd(&myh[keyOfU(b.w) >> 20], 1u);
        }
        if (i < hi) {
            uint4 a = p[i];
            atomicAdd(&myh[keyOfU(a.x) >> 20], 1u);
            atomicAdd(&myh[keyOfU(a.y) >> 20], 1u);
            atomicAdd(&myh[keyOfU(a.z) >> 20], 1u);
            atomicAdd(&myh[keyOfU(a.w) >> 20], 1u);
        }
        __syncthreads();
        unsigned* dst = gh + (size_t)n * HBINS;
        for (int b = tid; b < HBINS; b += NTHR) {
            unsigned v = lh[b] + lh[HBINS + b];
            if (v) atomicAdd(&dst[b], v);
        }
    }
    grid.sync();

    // ---------------- P2: threshold selection (blocks 0..7) -----------------
    if (bid < NB) {
        int n = bid;
        uint4 v0 = *(const uint4*)(gh + (size_t)n * HBINS + 8 * tid);
        uint4 v1 = *(const uint4*)(gh + (size_t)n * HBINS + 8 * tid + 4);
        unsigned s7 = v1.w, s6 = v1.z + s7, s5 = v1.y + s6, s4 = v1.x + s5;
        unsigned s3 = v0.w + s4, s2 = v0.z + s3, s1 = v0.y + s2, s0 = v0.x + s1;
        unsigned* L = sm32;
        L[tid] = s0;
        __syncthreads();
        for (int off = 1; off < NTHR; off <<= 1) {
            unsigned x = L[tid] + ((tid + off < NTHR) ? L[tid + off] : 0u);
            __syncthreads(); L[tid] = x; __syncthreads();
        }
        unsigned tail = (tid < NTHR - 1) ? L[tid + 1] : 0u;
        unsigned sf[9];
        sf[0] = s0 + tail; sf[1] = s1 + tail; sf[2] = s2 + tail; sf[3] = s3 + tail;
        sf[4] = s4 + tail; sf[5] = s5 + tail; sf[6] = s6 + tail; sf[7] = s7 + tail;
        sf[8] = tail;
#pragma unroll
        for (int e = 0; e < 8; ++e)
            if (sf[e] >= K_PRE && sf[e + 1] < K_PRE) selT12[n] = 8u * tid + e;
    }
    grid.sync();

    // ---------------- P3: compact into fixed slices (blocks 0..127) ---------
    if (bid < NB * CBLK) {
        int n = bid >> 4, cb = bid & 15;
        unsigned t12 = selT12[n];
        unsigned* cnt = sm32;
        if (tid == 0) *cnt = 0;
        __syncthreads();
        u64* slice = cand + (size_t)n * SORTN + (size_t)cb * SLICE;
        const uint4* p = cls4 + (size_t)n * (PER / 4);
        int lo = cb * 15000, hi = lo + 15000;    // PER/4/16
        for (int i = lo + tid; i < hi; i += NTHR) {
            uint4 v = p[i];
            unsigned k[4] = {keyOfU(v.x), keyOfU(v.y), keyOfU(v.z), keyOfU(v.w)};
            int i0 = i * 4;
            int a = i0 / HWSZ;               // uniform across the 4
            int r0 = i0 - a * HWSZ;
#pragma unroll
            for (int c = 0; c < 4; ++c) {
                if ((k[c] >> 20) >= t12) {
                    unsigned pos = atomicAdd(cnt, 1u);       // LDS atomic
                    if (pos < SLICE) {
                        unsigned idx = (unsigned)((r0 + c) * AN + a);
                        slice[pos] = ((u64)k[c] << 32) | (u64)(~idx);
                    }
                }
            }
        }
        __syncthreads();
        unsigned c0 = *cnt; if (c0 > SLICE) c0 = SLICE;
        for (unsigned t = c0 + tid; t < SLICE; t += NTHR) slice[t] = 0ull;
    }
    grid.sync();

    // ---------------- P4: bitonic sort + decode + partition (blocks 0..7) ---
    if (bid < NB) {
        int n = bid;
        u64* sb = smem;                      // PHI-padded, max idx PHI(4095)=4606
        u64 r[8];

#define CE(a_, b_, d_) { bool sw_ = (d_) ? (r[a_] < r[b_]) : (r[a_] > r[b_]); \
                         if (sw_) { u64 t_ = r[a_]; r[a_] = r[b_]; r[b_] = t_; } }

        {
            const u64* src = cand + (size_t)n * SORTN + 8 * tid;
#pragma unroll
            for (int e = 0; e < 8; ++e) r[e] = src[e];
            CE(0, 1, true)  CE(2, 3, false) CE(4, 5, true)  CE(6, 7, false)
            CE(0, 2, true)  CE(1, 3, true)  CE(4, 6, false) CE(5, 7, false)
            CE(0, 1, true)  CE(2, 3, true)  CE(4, 5, false) CE(6, 7, false)
#pragma unroll
            for (int e = 0; e < 8; ++e) sb[9 * tid + e] = r[e];   // PHI(8t+e)
            __syncthreads();
        }

        for (int k = 8; k <= SORTN; k <<= 1) {
            for (int j = k >> 1; j >= 8; j >>= 1) {
#pragma unroll
                for (int s = 0; s < 4; ++s) {
                    int c = tid + s * NTHR;
                    int i = ((c & ~(j - 1)) << 1) | (c & (j - 1));
                    int p = i | j;
                    bool dir = (i & k) == 0;
                    u64 a = sb[PHI(i)], b = sb[PHI(p)];
                    bool sw = dir ? (a < b) : (a > b);
                    if (sw) { sb[PHI(i)] = b; sb[PHI(p)] = a; }
                }
                __syncthreads();
            }
            {   // register pass: j = 4, 2, 1 (dir uniform per thread, k>=8)
                int base = 8 * tid;
                bool d = (base & k) == 0;
#pragma unroll
                for (int e = 0; e < 8; ++e) r[e] = sb[9 * tid + e];
                CE(0, 4, d) CE(1, 5, d) CE(2, 6, d) CE(3, 7, d)
                CE(0, 2, d) CE(1, 3, d) CE(4, 6, d) CE(5, 7, d)
                CE(0, 1, d) CE(2, 3, d) CE(4, 5, d) CE(6, 7, d)
#pragma unroll
                for (int e = 0; e < 8; ++e) sb[9 * tid + e] = r[e];
                __syncthreads();
            }
        }
#undef CE

        float fh = (float)(*pih);
        float fw = (float)(*piw);

        float bx[4][4]; float sc[4]; int pred[4];
#pragma unroll
        for (int q = 0; q < 4; ++q) {
            int t = tid + NTHR * q;
            pred[q] = 0; sc[q] = -1.0f;
            bx[q][0] = bx[q][1] = bx[q][2] = bx[q][3] = 0.f;
            if (t < K_PRE) {
                u64 e = sb[PHI(t)];
                unsigned key = (unsigned)(e >> 32);
                unsigned idx = ~((unsigned)e);
                float v = valOf(key);
                float s = 1.0f / (1.0f + expf(-v));
                int a = (int)(idx % AN);
                int rr = (int)(idx / AN);
                size_t base = ((size_t)(n * AN + a) * 4) * HWSZ + rr;
                float dx = regr[base];
                float dy = regr[base + HWSZ];
                float dw = regr[base + 2 * (size_t)HWSZ];
                float dh = regr[base + 3 * (size_t)HWSZ];
                float4 an4 = ((const float4*)anchors)[idx];
                float wa = an4.z - an4.x, ha = an4.w - an4.y;
                float cxa = an4.x + 0.5f * wa, cya = an4.y + 0.5f * ha;
                dw = fminf(dw, BBOX_CLIP_F); dh = fminf(dh, BBOX_CLIP_F);
                float cx = dx * wa + cxa, cy = dy * ha + cya;
                float w = wa * expf(dw), h = ha * expf(dh);
                float x1 = cx - 0.5f * w, y1 = cy - 0.5f * h;
                float x2 = cx + 0.5f * w, y2 = cy + 0.5f * h;
                x1 = fminf(fmaxf(x1, 0.f), fw);
                y1 = fminf(fmaxf(y1, 0.f), fh);
                x2 = fminf(fmaxf(x2, 0.f), fw);
                y2 = fminf(fmaxf(y2, 0.f), fh);
                bool valid = ((x2 - x1) >= 1.0f) && ((y2 - y1) >= 1.0f);
                bx[q][0] = x1; bx[q][1] = y1; bx[q][2] = x2; bx[q][3] = y2;
                sc[q] = s; pred[q] = valid ? 1 : 0;
            }
        }
        __syncthreads();

        // stable valid-first partition via per-wave ballots (2048 entries)
        u64* ww = smem + 4608;               // 32 u64
        int* wpfx = (int*)(smem + 4640);     // 33 ints
        int lane = tid & 63, wid = tid >> 6; // 8 waves
#pragma unroll
        for (int q = 0; q < 4; ++q) {
            u64 bal = __ballot(pred[q] != 0);
            if (lane == 0) ww[wid + 8 * q] = bal;
        }
        __syncthreads();
        if (tid == 0) {
            int s = 0;
#pragma unroll
            for (int w2 = 0; w2 < 32; ++w2) { wpfx[w2] = s; s += (int)__popcll(ww[w2]); }
            wpfx[32] = s;
        }
        __syncthreads();
        int V = wpfx[32];

#pragma unroll
        for (int q = 0; q < 4; ++q) {
            int t = tid + NTHR * q;
            if (t < K_PRE) {
                int wi = t >> 6;
                int before = wpfx[wi] + (int)__popcll(ww[wi] & ((1ull << (unsigned)lane) - 1ull));
                int pos = pred[q] ? before : (V + (t - before));
                float4 b4; b4.x = bx[q][0]; b4.y = bx[q][1]; b4.z = bx[q][2]; b4.w = bx[q][3];
                ((float4*)boxes_s)[(size_t)n * K_PRE + pos] = b4;
                scores_s[(size_t)n * K_PRE + pos] = pred[q] ? sc[q] : -1.0f;
            }
        }
    }
    grid.sync();

    // ---------------- P5: transposed IoU mask (32 col-blocks per image) -----
    {
        int n = bid >> 5, cb = bid & 31;
        int lane = tid & 63, w = tid >> 6;   // 8 waves
        float4* rowbuf = (float4*)smem;      // [8][64]
        int c = cb * 64 + lane;
        bool cok = c < K_PRE;
        float4 c4;
        if (cok) c4 = ((const float4*)boxes_s)[(size_t)n * K_PRE + c];
        else { c4.x = c4.y = c4.z = c4.w = 0.f; }
        float areaC = (c4.z - c4.x) * (c4.w - c4.y);

        for (int rb = w; rb < 32; rb += 8) {
            u64 bits = 0;
            if (rb <= cb) {
                int rr = rb * 64 + lane;
                float4 r4;
                if (rr < K_PRE) r4 = ((const float4*)boxes_s)[(size_t)n * K_PRE + rr];
                else { r4.x = r4.y = r4.z = r4.w = 0.f; }
                rowbuf[w * 64 + lane] = r4;  // wave-private row, no barrier needed
                if (cok) {
                    int bmax = c - rb * 64; if (bmax > 64) bmax = 64;
                    for (int b = 0; b < bmax; ++b) {
                        float4 q = rowbuf[w * 64 + b];
                        float ix = fminf(c4.z, q.z) - fmaxf(c4.x, q.x); ix = fmaxf(ix, 0.f);
                        float iy = fminf(c4.w, q.w) - fmaxf(c4.y, q.y); iy = fmaxf(iy, 0.f);
                        float inter = ix * iy;
                        float areaR = (q.z - q.x) * (q.w - q.y);
                        float iou = inter / (areaR + areaC - inter);
                        if (iou > NMS_TH) bits |= (1ull << b);
                    }
                }
            }
            maskT[((size_t)n * 32 + rb) * 2048 + c] = bits;
        }
    }
    grid.sync();

    // ---------------- P6: greedy NMS scan + output (blocks 0..7) ------------
    if (bid < NB) {
        int n = bid;
        float* ls = (float*)smem;            // 2048 floats
        u64* keptw = smem + 1024;            // 32 u64
        for (int i = tid; i < 2048; i += NTHR)
            ls[i] = (i < K_PRE) ? scores_s[(size_t)n * K_PRE + i] : -1.0f;
        if (tid < 32) keptw[tid] = 0ull;
        __syncthreads();

        if (tid < 64) {                      // single wave; wave-local LDS only
            int lane = tid;
            const u64* mb = maskT + (size_t)n * 32 * 2048;
            int kept_total = 0;

            u64 wv[32];
#pragma unroll
            for (int rb = 0; rb < 32; ++rb) wv[rb] = mb[(size_t)rb * 2048 + lane];

            for (int f = 0; f < 32; ++f) {
                int c = f * 64 + lane;

                u64 wn[32];
                if (f < 31) {
                    int cn = c + 64;
#pragma unroll
                    for (int rb = 0; rb < 32; ++rb) wn[rb] = mb[(size_t)rb * 2048 + cn];
                }

                u64 hit = 0;
#pragma unroll
                for (int rb = 0; rb < 32; ++rb) hit |= (wv[rb] & keptw[rb]);
                bool ext = hit != 0ull;
                u64 diag = wv[f];

                bool v = (ls[c] >= 0.0f) && !ext;
                u64 kept = __ballot(v);
                while (true) {
                    u64 nk = __ballot(v && ((diag & kept) == 0ull));
                    if (nk == kept) break;
                    kept = nk;
                }

                if ((kept >> lane) & 1ull) {
                    int rank = kept_total + (int)__popcll(kept & ((1ull << lane) - 1ull));
                    if (rank < K_POST) {
                        float4 b4 = ((const float4*)boxes_s)[(size_t)n * K_PRE + c];
                        ((float4*)out)[(size_t)n * K_POST + rank] = b4;
                        out[(size_t)NB * K_POST * 4 + (size_t)n * K_POST + rank] = ls[c];
                    }
                }
                kept_total += (int)__popcll(kept);
                if (lane == 0) keptw[f] = kept;   // same-wave LDS, in-order
                if (kept_total >= K_POST || f == 31) break;
#pragma unroll
                for (int rb = 0; rb < 32; ++rb) wv[rb] = wn[rb];
            }

            // zero output tail (every output byte written each replay)
            int start = (kept_total < K_POST) ? kept_total : K_POST;
            float4 z4; z4.x = z4.y = z4.z = z4.w = 0.f;
            for (int rk = start + lane; rk < K_POST; rk += 64) {
                ((float4*)out)[(size_t)n * K_POST + rk] = z4;
                out[(size_t)NB * K_POST * 4 + (size_t)n * K_POST + rk] = 0.f;
            }
        }
    }
}

extern "C" void kernel_launch(void* const* d_in, const int* in_sizes, int n_in,
                              void* d_out, int out_size, void* d_ws, size_t ws_size,
                              hipStream_t stream) {
    const uint4* cls4    = (const uint4*)d_in[0];
    const float* regr    = (const float*)d_in[1];
    const float* anchors = (const float*)d_in[2];
    const int*   pih     = (const int*)d_in[3];
    const int*   piw     = (const int*)d_in[4];
    float* out = (float*)d_out;

    char* w = (char*)d_ws;
    // Region A [0, 4 MiB), time-multiplexed across grid.sync boundaries:
    //   gh    (P0-P2)   8*4096*4    =   131,072
    //   cand  (P3-P4)   8*4096*8    =   262,144
    //   maskT (P5-P6)   8*32*2048*8 = 4,194,304
    unsigned* gh      = (unsigned*)(w + 0);
    u64*      cand    = (u64*)(w + 0);
    u64*      maskT   = (u64*)(w + 0);
    unsigned* selT12  = (unsigned*)(w + 4194304);      // 32 B
    float*    boxes_s = (float*)(w + 4194560);         // 256,000
    float*    scores_s= (float*)(w + 4450560);         //  64,000
    // total 4,514,560 bytes

    void* args[] = { (void*)&cls4, (void*)&regr, (void*)&anchors, (void*)&pih,
                     (void*)&piw, (void*)&gh, (void*)&selT12, (void*)&cand,
                     (void*)&boxes_s, (void*)&scores_s, (void*)&maskT, (void*)&out };
    hipLaunchCooperativeKernel((const void*)k_fused, dim3(NBLK), dim3(NTHR),
                               args, 0, stream);
    (void)in_sizes; (void)n_in; (void)ws_size; (void)out_size;
}

// Round 8
// 176.500 us; speedup vs baseline: 1.4651x; 1.4651x over previous
//
#include <hip/hip_runtime.h>
#include <hip/hip_bf16.h>
#include <stdint.h>

typedef unsigned long long u64;

#define AN 15
#define HH 200
#define WW 320
#define HWSZ (HH*WW)          // 64000
#define PER (AN*HWSZ)         // 960000 anchors per image
#define NB 8
#define K_PRE 2000
#define K_POST 1000
#define SORTN 4096
#define HBINS 4096
#define HBLK 64               // hist blocks per image
#define CBLK 16               // compact blocks per image
#define SLICE (SORTN/CBLK)    // 256 candidate slots per compact block
#define NMS_TH 0.7f
#define BBOX_CLIP_F 4.135166556742356f   // log(1000/16)

// padded LDS index for the sort: lane stride 72B -> <=4-way bank conflicts
#define PHI(x) ((x) + ((x) >> 3))

__device__ __forceinline__ unsigned keyOfU(unsigned u) {
    return (u & 0x80000000u) ? ~u : (u | 0x80000000u);
}
__device__ __forceinline__ float valOf(unsigned k) {
    unsigned u = (k & 0x80000000u) ? (k ^ 0x80000000u) : ~k;
    return __uint_as_float(u);
}

// ---------- zero-init gh ----------------------------------------------------
__global__ __launch_bounds__(256)
void z_init(uint4* __restrict__ gh4) {
    gh4[blockIdx.x * 256 + threadIdx.x] = make_uint4(0, 0, 0, 0);
}

// ---------- pass 1: dual private 12-bit hist -> global atomic flush ---------
__global__ __launch_bounds__(256)
void k_hist(const uint4* __restrict__ cls4, unsigned* __restrict__ gh) {
    int n = blockIdx.y;
    __shared__ unsigned lh[2][HBINS];          // 32 KB, even/odd thread copies
    for (int b = threadIdx.x; b < HBINS; b += 256) { lh[0][b] = 0; lh[1][b] = 0; }
    __syncthreads();
    unsigned* myh = lh[threadIdx.x & 1];
    const uint4* p = cls4 + (size_t)n * (PER / 4);
    int stride = gridDim.x * 256;
    int i = blockIdx.x * 256 + threadIdx.x;
    for (; i + stride < PER / 4; i += 2 * stride) {
        uint4 a = p[i];
        uint4 b = p[i + stride];
        atomicAdd(&myh[keyOfU(a.x) >> 20], 1u);
        atomicAdd(&myh[keyOfU(a.y) >> 20], 1u);
        atomicAdd(&myh[keyOfU(a.z) >> 20], 1u);
        atomicAdd(&myh[keyOfU(a.w) >> 20], 1u);
        atomicAdd(&myh[keyOfU(b.x) >> 20], 1u);
        atomicAdd(&myh[keyOfU(b.y) >> 20], 1u);
        atomicAdd(&myh[keyOfU(b.z) >> 20], 1u);
        atomicAdd(&myh[keyOfU(b.w) >> 20], 1u);
    }
    if (i < PER / 4) {
        uint4 a = p[i];
        atomicAdd(&myh[keyOfU(a.x) >> 20], 1u);
        atomicAdd(&myh[keyOfU(a.y) >> 20], 1u);
        atomicAdd(&myh[keyOfU(a.z) >> 20], 1u);
        atomicAdd(&myh[keyOfU(a.w) >> 20], 1u);
    }
    __syncthreads();
    unsigned* dst = gh + (size_t)n * HBINS;
    for (int b = threadIdx.x; b < HBINS; b += 256) {
        unsigned v = lh[0][b] + lh[1][b];
        if (v) atomicAdd(&dst[b], v);      // fire-and-forget
    }
}

// ---------- suffix-scan of per-image hist -> 12-bit threshold ---------------
__global__ __launch_bounds__(1024)
void k_sel(const unsigned* __restrict__ gh, unsigned* __restrict__ selT12) {
    int n = blockIdx.x, t = threadIdx.x;
    __shared__ unsigned L[1024];
    uint4 v = *(const uint4*)(gh + (size_t)n * HBINS + 4 * t);
    unsigned s3 = v.w, s2 = v.z + s3, s1 = v.y + s2, s0 = v.x + s1;
    L[t] = s0;
    __syncthreads();
    for (int off = 1; off < 1024; off <<= 1) {
        unsigned x = L[t] + ((t + off < 1024) ? L[t + off] : 0u);
        __syncthreads(); L[t] = x; __syncthreads();
    }
    unsigned tail = (t < 1023) ? L[t + 1] : 0u;
    unsigned sf0 = s0 + tail, sf1 = s1 + tail, sf2 = s2 + tail, sf3 = s3 + tail;
    if (sf0 >= K_PRE && sf1 < K_PRE) selT12[n] = 4u * t + 0u;
    if (sf1 >= K_PRE && sf2 < K_PRE) selT12[n] = 4u * t + 1u;
    if (sf2 >= K_PRE && sf3 < K_PRE) selT12[n] = 4u * t + 2u;
    if (sf3 >= K_PRE && tail < K_PRE) selT12[n] = 4u * t + 3u;
}

// ---------- compact candidates into fixed per-block slices ------------------
__global__ __launch_bounds__(256)
void k_compact(const uint4* __restrict__ cls4, const unsigned* __restrict__ selT12,
               u64* __restrict__ cand) {
    int n = blockIdx.y;
    unsigned t12 = selT12[n];
    __shared__ unsigned cnt;
    if (threadIdx.x == 0) cnt = 0;
    __syncthreads();
    u64* slice = cand + (size_t)n * SORTN + (size_t)blockIdx.x * SLICE;
    const uint4* p = cls4 + (size_t)n * (PER / 4);
    int stride = gridDim.x * 256;
    for (int i4 = blockIdx.x * 256 + threadIdx.x; i4 < PER / 4; i4 += stride) {
        uint4 v = p[i4];
        unsigned k[4] = {keyOfU(v.x), keyOfU(v.y), keyOfU(v.z), keyOfU(v.w)};
        int i0 = i4 * 4;
        int a = i0 / HWSZ;                 // uniform across the 4 (HWSZ % 4 == 0)
        int r0 = i0 - a * HWSZ;
#pragma unroll
        for (int c = 0; c < 4; ++c) {
            if ((k[c] >> 20) >= t12) {
                unsigned pos = atomicAdd(&cnt, 1u);        // LDS atomic only
                if (pos < SLICE) {
                    unsigned idx = (unsigned)((r0 + c) * AN + a);
                    slice[pos] = ((u64)k[c] << 32) | (u64)(~idx);
                }
            }
        }
    }
    __syncthreads();
    unsigned c0 = cnt; if (c0 > SLICE) c0 = SLICE;
    for (unsigned t = c0 + threadIdx.x; t < SLICE; t += 256) slice[t] = 0ull;
}

// ---------- per-image: register-hybrid bitonic sort (PHI-padded LDS) --------
// sorts cand[n] descending in-place (global round-trip, coalesced)
__global__ __launch_bounds__(512)
void k_sort(u64* __restrict__ cand) {
    int n = blockIdx.x;
    int tid = threadIdx.x;
    __shared__ u64 sb[PHI(SORTN - 1) + 1];   // 4607 u64 = 36.9 KB
    u64 r[8];

#define CE(a_, b_, d_) { bool sw_ = (d_) ? (r[a_] < r[b_]) : (r[a_] > r[b_]); \
                         if (sw_) { u64 t_ = r[a_]; r[a_] = r[b_]; r[b_] = t_; } }

    {   // load own 8 elements, run k=2 and k=4 levels fully in registers
        const u64* src = cand + (size_t)n * SORTN + 8 * tid;
#pragma unroll
        for (int e = 0; e < 8; ++e) r[e] = src[e];
        CE(0, 1, true)  CE(2, 3, false) CE(4, 5, true)  CE(6, 7, false)
        CE(0, 2, true)  CE(1, 3, true)  CE(4, 6, false) CE(5, 7, false)
        CE(0, 1, true)  CE(2, 3, true)  CE(4, 5, false) CE(6, 7, false)
#pragma unroll
        for (int e = 0; e < 8; ++e) sb[9 * tid + e] = r[e];   // PHI(8t+e)
        __syncthreads();
    }

    for (int k = 8; k <= SORTN; k <<= 1) {
        for (int j = k >> 1; j >= 8; j >>= 1) {
#pragma unroll
            for (int s = 0; s < 4; ++s) {
                int c = tid + s * 512;
                int i = ((c & ~(j - 1)) << 1) | (c & (j - 1));
                int p = i | j;
                bool dir = (i & k) == 0;
                u64 a = sb[PHI(i)], b = sb[PHI(p)];
                bool sw = dir ? (a < b) : (a > b);
                if (sw) { sb[PHI(i)] = b; sb[PHI(p)] = a; }
            }
            __syncthreads();
        }
        {   // register pass: j = 4, 2, 1 (dir uniform per thread for k>=8)
            bool d = ((8 * tid) & k) == 0;
#pragma unroll
            for (int e = 0; e < 8; ++e) r[e] = sb[9 * tid + e];
            CE(0, 4, d) CE(1, 5, d) CE(2, 6, d) CE(3, 7, d)
            CE(0, 2, d) CE(1, 3, d) CE(4, 6, d) CE(5, 7, d)
            CE(0, 1, d) CE(2, 3, d) CE(4, 5, d) CE(6, 7, d)
#pragma unroll
            for (int e = 0; e < 8; ++e) sb[9 * tid + e] = r[e];
            __syncthreads();
        }
    }
#undef CE

    // coalesced write-back of the sorted array
    for (int t = tid; t < SORTN; t += 512)
        cand[(size_t)n * SORTN + t] = sb[PHI(t)];
}

// ---------- decode top-2000 + stable valid-first partition (wide gathers) ---
__global__ __launch_bounds__(1024)
void k_decode(const float* __restrict__ reg, const float* __restrict__ anchors,
              const int* __restrict__ pih, const int* __restrict__ piw,
              const u64* __restrict__ cand,
              float* __restrict__ boxes_s, float* __restrict__ scores_s) {
    int n = blockIdx.x;
    int tid = threadIdx.x;
    float fh = (float)(*pih);
    float fw = (float)(*piw);

    float bx[2][4]; float sc[2]; int pred[2];
#pragma unroll
    for (int q = 0; q < 2; ++q) {
        int t = tid + 1024 * q;
        pred[q] = 0; sc[q] = -1.0f;
        bx[q][0] = bx[q][1] = bx[q][2] = bx[q][3] = 0.f;
        if (t < K_PRE) {
            u64 e = cand[(size_t)n * SORTN + t];
            unsigned key = (unsigned)(e >> 32);
            unsigned idx = ~((unsigned)e);
            float v = valOf(key);
            float s = 1.0f / (1.0f + expf(-v));
            int a = (int)(idx % AN);
            int rr = (int)(idx / AN);
            size_t base = ((size_t)(n * AN + a) * 4) * HWSZ + rr;
            float dx = reg[base];
            float dy = reg[base + HWSZ];
            float dw = reg[base + 2 * (size_t)HWSZ];
            float dh = reg[base + 3 * (size_t)HWSZ];
            float4 an4 = ((const float4*)anchors)[idx];
            float wa = an4.z - an4.x, ha = an4.w - an4.y;
            float cxa = an4.x + 0.5f * wa, cya = an4.y + 0.5f * ha;
            dw = fminf(dw, BBOX_CLIP_F); dh = fminf(dh, BBOX_CLIP_F);
            float cx = dx * wa + cxa, cy = dy * ha + cya;
            float w = wa * expf(dw), h = ha * expf(dh);
            float x1 = cx - 0.5f * w, y1 = cy - 0.5f * h;
            float x2 = cx + 0.5f * w, y2 = cy + 0.5f * h;
            x1 = fminf(fmaxf(x1, 0.f), fw);
            y1 = fminf(fmaxf(y1, 0.f), fh);
            x2 = fminf(fmaxf(x2, 0.f), fw);
            y2 = fminf(fmaxf(y2, 0.f), fh);
            bool valid = ((x2 - x1) >= 1.0f) && ((y2 - y1) >= 1.0f);
            bx[q][0] = x1; bx[q][1] = y1; bx[q][2] = x2; bx[q][3] = y2;
            sc[q] = s; pred[q] = valid ? 1 : 0;
        }
    }

    // stable valid-first partition via per-wave ballots (2048 entries)
    __shared__ u64 ww[32];
    __shared__ int wpfx[33];
    int lane = tid & 63, wid = tid >> 6;     // 16 waves
#pragma unroll
    for (int q = 0; q < 2; ++q) {
        u64 bal = __ballot(pred[q] != 0);
        if (lane == 0) ww[wid + 16 * q] = bal;
    }
    __syncthreads();
    if (tid == 0) {
        int s = 0;
#pragma unroll
        for (int w2 = 0; w2 < 32; ++w2) { wpfx[w2] = s; s += (int)__popcll(ww[w2]); }
        wpfx[32] = s;
    }
    __syncthreads();
    int V = wpfx[32];

#pragma unroll
    for (int q = 0; q < 2; ++q) {
        int t = tid + 1024 * q;
        if (t < K_PRE) {
            int wi = t >> 6;
            int before = wpfx[wi] + (int)__popcll(ww[wi] & ((1ull << (unsigned)lane) - 1ull));
            int pos = pred[q] ? before : (V + (t - before));
            float4 b4; b4.x = bx[q][0]; b4.y = bx[q][1]; b4.z = bx[q][2]; b4.w = bx[q][3];
            ((float4*)boxes_s)[(size_t)n * K_PRE + pos] = b4;
            scores_s[(size_t)n * K_PRE + pos] = pred[q] ? sc[q] : -1.0f;
        }
    }
}

// ---------- transposed IoU mask: maskT[n][rowblk][col] = incoming edges -----
__global__ __launch_bounds__(256)
void k_maskT(const float* __restrict__ boxes_s, u64* __restrict__ maskT) {
    int n = blockIdx.y, cb = blockIdx.x;
    int lane = threadIdx.x & 63, w = threadIdx.x >> 6;
    __shared__ float4 rowbuf[4][64];
    int c = cb * 64 + lane;
    bool cok = c < K_PRE;
    float4 c4;
    if (cok) c4 = ((const float4*)boxes_s)[(size_t)n * K_PRE + c];
    else { c4.x = c4.y = c4.z = c4.w = 0.f; }
    float areaC = (c4.z - c4.x) * (c4.w - c4.y);

    for (int rb = w; rb < 32; rb += 4) {
        u64 bits = 0;
        if (rb <= cb) {
            int r = rb * 64 + lane;
            float4 r4;
            if (r < K_PRE) r4 = ((const float4*)boxes_s)[(size_t)n * K_PRE + r];
            else { r4.x = r4.y = r4.z = r4.w = 0.f; }
            rowbuf[w][lane] = r4;
            if (cok) {
                int bmax = c - rb * 64; if (bmax > 64) bmax = 64;
                for (int b = 0; b < bmax; ++b) {
                    float4 q = rowbuf[w][b];
                    float ix = fminf(c4.z, q.z) - fmaxf(c4.x, q.x); ix = fmaxf(ix, 0.f);
                    float iy = fminf(c4.w, q.w) - fmaxf(c4.y, q.y); iy = fmaxf(iy, 0.f);
                    float inter = ix * iy;
                    float areaR = (q.z - q.x) * (q.w - q.y);
                    float iou = inter / (areaR + areaC - inter);
                    if (iou > NMS_TH) bits |= (1ull << b);
                }
            }
        }
        maskT[((size_t)n * 32 + rb) * 2048 + c] = bits;
    }
}

// ---------- greedy NMS: ballot-fixpoint per 64-block + output (tail zeroed) -
__global__ __launch_bounds__(64)
void k_scanT(const u64* __restrict__ maskT, const float* __restrict__ boxes_s,
             const float* __restrict__ scores_s, float* __restrict__ out) {
    int n = blockIdx.x;
    int lane = threadIdx.x;       // 64 threads, single wave
    __shared__ float ls[2048];
    __shared__ u64 keptw[32];
    for (int i = lane; i < 2048; i += 64)
        ls[i] = (i < K_PRE) ? scores_s[(size_t)n * K_PRE + i] : -1.0f;
    if (lane < 32) keptw[lane] = 0ull;
    __syncthreads();

    const u64* mb = maskT + (size_t)n * 32 * 2048;
    int kept_total = 0;

    u64 wv[32];
#pragma unroll
    for (int rb = 0; rb < 32; ++rb) wv[rb] = mb[(size_t)rb * 2048 + lane];

    for (int f = 0; f < 32; ++f) {
        int c = f * 64 + lane;

        u64 wn[32];
        if (f < 31) {
            int cn = c + 64;
#pragma unroll
            for (int rb = 0; rb < 32; ++rb) wn[rb] = mb[(size_t)rb * 2048 + cn];
        }

        u64 hit = 0;
#pragma unroll
        for (int rb = 0; rb < 32; ++rb) hit |= (wv[rb] & keptw[rb]);
        bool ext = hit != 0ull;
        u64 diag = wv[f];

        bool v = (ls[c] >= 0.0f) && !ext;
        u64 kept = __ballot(v);
        while (true) {
            u64 nk = __ballot(v && ((diag & kept) == 0ull));
            if (nk == kept) break;
            kept = nk;
        }

        if ((kept >> lane) & 1ull) {
            int rank = kept_total + (int)__popcll(kept & ((1ull << lane) - 1ull));
            if (rank < K_POST) {
                float4 b4 = ((const float4*)boxes_s)[(size_t)n * K_PRE + c];
                ((float4*)out)[(size_t)n * K_POST + rank] = b4;
                out[(size_t)NB * K_POST * 4 + (size_t)n * K_POST + rank] = ls[c];
            }
        }
        kept_total += (int)__popcll(kept);
        if (lane == 0) keptw[f] = kept;
        if (kept_total >= K_POST || f == 31) break;
#pragma unroll
        for (int rb = 0; rb < 32; ++rb) wv[rb] = wn[rb];
    }

    // zero output tail (every output byte written each replay)
    int start = (kept_total < K_POST) ? kept_total : K_POST;
    float4 z4; z4.x = z4.y = z4.z = z4.w = 0.f;
    for (int rk = start + lane; rk < K_POST; rk += 64) {
        ((float4*)out)[(size_t)n * K_POST + rk] = z4;
        out[(size_t)NB * K_POST * 4 + (size_t)n * K_POST + rk] = 0.f;
    }
}

extern "C" void kernel_launch(void* const* d_in, const int* in_sizes, int n_in,
                              void* d_out, int out_size, void* d_ws, size_t ws_size,
                              hipStream_t stream) {
    const float* cls     = (const float*)d_in[0];
    const float* regr    = (const float*)d_in[1];
    const float* anchors = (const float*)d_in[2];
    const int*   pih     = (const int*)d_in[3];
    const int*   piw     = (const int*)d_in[4];
    float* out = (float*)d_out;

    char* w = (char*)d_ws;
    // Region A [0, 4 MiB), time-multiplexed (strict stream order):
    //   gh    (z_init -> k_hist -> k_sel)      8*4096*4  =   131,072
    //   cand  (k_compact -> k_sort -> k_decode) 8*4096*8 =   262,144
    //   maskT (k_maskT -> k_scanT)             8*32*2048*8 = 4,194,304
    unsigned* gh      = (unsigned*)(w + 0);
    u64*      cand    = (u64*)(w + 0);
    u64*      maskT   = (u64*)(w + 0);
    unsigned* selT12    = (unsigned*)(w + 4194304);    // 32 B
    float*    boxes_s   = (float*)(w + 4194560);       // 8*2000*4*4 = 256,000
    float*    scores_s  = (float*)(w + 4450560);       // 8*2000*4   =  64,000
    // total 4,514,560 bytes

    z_init<<<(NB * HBINS * 4) / 4096, 256, 0, stream>>>((uint4*)gh);
    k_hist<<<dim3(HBLK, NB), 256, 0, stream>>>((const uint4*)cls, gh);
    k_sel<<<NB, 1024, 0, stream>>>(gh, selT12);
    k_compact<<<dim3(CBLK, NB), 256, 0, stream>>>((const uint4*)cls, selT12, cand);
    k_sort<<<NB, 512, 0, stream>>>(cand);
    k_decode<<<NB, 1024, 0, stream>>>(regr, anchors, pih, piw,
                                      cand, boxes_s, scores_s);
    k_maskT<<<dim3(32, NB), 256, 0, stream>>>(boxes_s, maskT);
    k_scanT<<<NB, 64, 0, stream>>>(maskT, boxes_s, scores_s, out);
    (void)in_sizes; (void)n_in; (void)ws_size;
}